// Round 1
// baseline (177.790 us; speedup 1.0000x reference)
//
#include <hip/hip_runtime.h>
#include <hip/hip_bf16.h>

// CenterLoss: B=8192 samples, D=512 feat, C=10000 classes.
// out = mean_i clip(||x_i - centers[labels_i]||^2, 1e-12, 1e12)
//
// One wave (64 lanes) per sample. D=512 floats = 128 float4 -> 2 float4
// loads per lane from x and from the gathered center row. Wave
// shuffle-reduce, lane 0 atomicAdd(dist/B) into d_out.

#define D_FEAT 512

__global__ void init_out_kernel(float* out) {
    if (threadIdx.x == 0) out[0] = 0.0f;
}

__global__ __launch_bounds__(256) void center_loss_kernel(
    const float* __restrict__ x,
    const int* __restrict__ labels,
    const float* __restrict__ centers,
    float* __restrict__ out,
    int B, float inv_B)
{
    const int gtid = blockIdx.x * blockDim.x + threadIdx.x;
    const int sample = gtid >> 6;          // one wave per sample
    const int lane = threadIdx.x & 63;
    if (sample >= B) return;

    const int lbl = labels[sample];

    const float4* __restrict__ xp = (const float4*)(x + (size_t)sample * D_FEAT);
    const float4* __restrict__ cp = (const float4*)(centers + (size_t)lbl * D_FEAT);

    // 128 float4 per row / 64 lanes = 2 per lane; coalesced 16B/lane.
    float4 xa = xp[lane];
    float4 xb = xp[lane + 64];
    float4 ca = cp[lane];
    float4 cb = cp[lane + 64];

    float d0 = xa.x - ca.x, d1 = xa.y - ca.y, d2 = xa.z - ca.z, d3 = xa.w - ca.w;
    float d4 = xb.x - cb.x, d5 = xb.y - cb.y, d6 = xb.z - cb.z, d7 = xb.w - cb.w;

    float acc = d0*d0 + d1*d1 + d2*d2 + d3*d3 + d4*d4 + d5*d5 + d6*d6 + d7*d7;

    // wave-64 butterfly reduce
    #pragma unroll
    for (int off = 32; off > 0; off >>= 1)
        acc += __shfl_down(acc, off, 64);

    if (lane == 0) {
        float dist = fminf(fmaxf(acc, 1e-12f), 1e12f);
        atomicAdd(out, dist * inv_B);
    }
}

extern "C" void kernel_launch(void* const* d_in, const int* in_sizes, int n_in,
                              void* d_out, int out_size, void* d_ws, size_t ws_size,
                              hipStream_t stream) {
    const float* x       = (const float*)d_in[0];
    const int*   labels  = (const int*)d_in[1];
    const float* centers = (const float*)d_in[2];
    float* out = (float*)d_out;

    const int B = in_sizes[1];              // 8192

    init_out_kernel<<<1, 64, 0, stream>>>(out);

    const int waves_per_block = 256 / 64;   // 4 samples per block
    const int grid = (B + waves_per_block - 1) / waves_per_block;
    center_loss_kernel<<<grid, 256, 0, stream>>>(x, labels, centers, out, B, 1.0f / (float)B);
}

// Round 2
// 81.413 us; speedup vs baseline: 2.1838x; 2.1838x over previous
//
#include <hip/hip_runtime.h>
#include <hip/hip_bf16.h>

// CenterLoss: B=8192 samples, D=512 feat, C=10000 classes.
// out = mean_i clip(||x_i - centers[labels_i]||^2, 1e-12, 1e12)
//
// R1 post-mortem: wave-per-sample + 8192 same-address atomicAdds was
// atomic-throughput-bound (one per ~31.6 cyc => 108 us). R2: block-level
// reduction so only 256 atomics total; labels prefetched per wave so all
// 16 float4 loads per wave are independent and can be in flight together.

#define D_FEAT 512
#define THREADS 512          // 8 waves per block
#define WAVES_PER_BLOCK 8
#define SAMPLES_PER_WAVE 4
#define BLOCKS 256           // 256*8*4 = 8192 samples

__global__ void init_out_kernel(float* out) {
    if (threadIdx.x == 0) out[0] = 0.0f;
}

__global__ __launch_bounds__(THREADS) void center_loss_kernel(
    const float* __restrict__ x,
    const int* __restrict__ labels,
    const float* __restrict__ centers,
    float* __restrict__ out,
    float inv_B)
{
    const int wave = threadIdx.x >> 6;
    const int lane = threadIdx.x & 63;
    const int sample0 = (blockIdx.x * WAVES_PER_BLOCK + wave) * SAMPLES_PER_WAVE;

    // Prefetch this wave's labels (same addr across lanes -> broadcast).
    int lbl[SAMPLES_PER_WAVE];
    #pragma unroll
    for (int j = 0; j < SAMPLES_PER_WAVE; ++j)
        lbl[j] = labels[sample0 + j];

    // Issue all loads (16 x float4 per lane across 4 samples) before compute.
    float4 xa[SAMPLES_PER_WAVE], xb[SAMPLES_PER_WAVE];
    float4 ca[SAMPLES_PER_WAVE], cb[SAMPLES_PER_WAVE];
    #pragma unroll
    for (int j = 0; j < SAMPLES_PER_WAVE; ++j) {
        const float4* __restrict__ xp =
            (const float4*)(x + (size_t)(sample0 + j) * D_FEAT);
        const float4* __restrict__ cp =
            (const float4*)(centers + (size_t)lbl[j] * D_FEAT);
        xa[j] = xp[lane];       xb[j] = xp[lane + 64];
        ca[j] = cp[lane];       cb[j] = cp[lane + 64];
    }

    float wave_acc = 0.0f;
    #pragma unroll
    for (int j = 0; j < SAMPLES_PER_WAVE; ++j) {
        float d0 = xa[j].x - ca[j].x, d1 = xa[j].y - ca[j].y;
        float d2 = xa[j].z - ca[j].z, d3 = xa[j].w - ca[j].w;
        float d4 = xb[j].x - cb[j].x, d5 = xb[j].y - cb[j].y;
        float d6 = xb[j].z - cb[j].z, d7 = xb[j].w - cb[j].w;
        float acc = d0*d0 + d1*d1 + d2*d2 + d3*d3
                  + d4*d4 + d5*d5 + d6*d6 + d7*d7;
        // butterfly reduce: all lanes end with the per-sample total
        #pragma unroll
        for (int off = 32; off > 0; off >>= 1)
            acc += __shfl_xor(acc, off, 64);
        // per-sample clip, then accumulate (value identical on all lanes)
        wave_acc += fminf(fmaxf(acc, 1e-12f), 1e12f);
    }

    __shared__ float s_part[WAVES_PER_BLOCK];
    if (lane == 0) s_part[wave] = wave_acc;
    __syncthreads();

    if (threadIdx.x == 0) {
        float block_sum = 0.0f;
        #pragma unroll
        for (int w = 0; w < WAVES_PER_BLOCK; ++w) block_sum += s_part[w];
        atomicAdd(out, block_sum * inv_B);
    }
}

extern "C" void kernel_launch(void* const* d_in, const int* in_sizes, int n_in,
                              void* d_out, int out_size, void* d_ws, size_t ws_size,
                              hipStream_t stream) {
    const float* x       = (const float*)d_in[0];
    const int*   labels  = (const int*)d_in[1];
    const float* centers = (const float*)d_in[2];
    float* out = (float*)d_out;

    const int B = in_sizes[1];              // 8192

    init_out_kernel<<<1, 64, 0, stream>>>(out);
    center_loss_kernel<<<BLOCKS, THREADS, 0, stream>>>(
        x, labels, centers, out, 1.0f / (float)B);
}

// Round 3
// 79.230 us; speedup vs baseline: 2.2440x; 1.0275x over previous
//
#include <hip/hip_runtime.h>
#include <hip/hip_bf16.h>

// CenterLoss: B=8192 samples, D=512 feat, C=10000 classes.
// out = mean_i clip(||x_i - centers[labels_i]||^2, 1e-12, 1e12)
//
// R1: wave-per-sample + 8192 same-address atomics -> atomic-bound, 108 us.
// R2: block reduction + 256 atomics -> kernel ~11.6 us; bench dominated by
//     harness's 256 MiB d_ws poison fill (~42 us, untouchable).
// R3: remove the 256-atomic same-cacheline tail (~3.4 us @ 31.6 cyc/atomic)
//     and the init kernel: blocks store uncontended partials to d_ws, then a
//     1-wave reduce kernel sums 256 floats -> out. No atomics anywhere.

#define D_FEAT 512
#define THREADS 512          // 8 waves per block
#define WAVES_PER_BLOCK 8
#define SAMPLES_PER_WAVE 4
#define BLOCKS 256           // 256*8*4 = 8192 samples

__global__ __launch_bounds__(THREADS) void center_loss_partial_kernel(
    const float* __restrict__ x,
    const int* __restrict__ labels,
    const float* __restrict__ centers,
    float* __restrict__ partials)
{
    const int wave = threadIdx.x >> 6;
    const int lane = threadIdx.x & 63;
    const int sample0 = (blockIdx.x * WAVES_PER_BLOCK + wave) * SAMPLES_PER_WAVE;

    // Wave-uniform label prefetch (scalar loads).
    int lbl[SAMPLES_PER_WAVE];
    #pragma unroll
    for (int j = 0; j < SAMPLES_PER_WAVE; ++j)
        lbl[j] = labels[sample0 + j];

    // All 16 float4 loads per lane issued before any compute.
    float4 xa[SAMPLES_PER_WAVE], xb[SAMPLES_PER_WAVE];
    float4 ca[SAMPLES_PER_WAVE], cb[SAMPLES_PER_WAVE];
    #pragma unroll
    for (int j = 0; j < SAMPLES_PER_WAVE; ++j) {
        const float4* __restrict__ xp =
            (const float4*)(x + (size_t)(sample0 + j) * D_FEAT);
        const float4* __restrict__ cp =
            (const float4*)(centers + (size_t)lbl[j] * D_FEAT);
        xa[j] = xp[lane];       xb[j] = xp[lane + 64];
        ca[j] = cp[lane];       cb[j] = cp[lane + 64];
    }

    float wave_acc = 0.0f;
    #pragma unroll
    for (int j = 0; j < SAMPLES_PER_WAVE; ++j) {
        float d0 = xa[j].x - ca[j].x, d1 = xa[j].y - ca[j].y;
        float d2 = xa[j].z - ca[j].z, d3 = xa[j].w - ca[j].w;
        float d4 = xb[j].x - cb[j].x, d5 = xb[j].y - cb[j].y;
        float d6 = xb[j].z - cb[j].z, d7 = xb[j].w - cb[j].w;
        float acc = d0*d0 + d1*d1 + d2*d2 + d3*d3
                  + d4*d4 + d5*d5 + d6*d6 + d7*d7;
        // butterfly reduce: all lanes end with the per-sample total
        #pragma unroll
        for (int off = 32; off > 0; off >>= 1)
            acc += __shfl_xor(acc, off, 64);
        wave_acc += fminf(fmaxf(acc, 1e-12f), 1e12f);   // per-sample clip
    }

    __shared__ float s_part[WAVES_PER_BLOCK];
    if (lane == 0) s_part[wave] = wave_acc;
    __syncthreads();

    if (threadIdx.x == 0) {
        float block_sum = 0.0f;
        #pragma unroll
        for (int w = 0; w < WAVES_PER_BLOCK; ++w) block_sum += s_part[w];
        partials[blockIdx.x] = block_sum;    // uncontended store, no atomic
    }
}

__global__ __launch_bounds__(64) void center_loss_reduce_kernel(
    const float* __restrict__ partials,
    float* __restrict__ out,
    float inv_B)
{
    const int lane = threadIdx.x;            // 64 lanes x float4 = 256 floats
    float4 v = ((const float4*)partials)[lane];
    float acc = v.x + v.y + v.z + v.w;
    #pragma unroll
    for (int off = 32; off > 0; off >>= 1)
        acc += __shfl_xor(acc, off, 64);
    if (lane == 0) out[0] = acc * inv_B;
}

extern "C" void kernel_launch(void* const* d_in, const int* in_sizes, int n_in,
                              void* d_out, int out_size, void* d_ws, size_t ws_size,
                              hipStream_t stream) {
    const float* x       = (const float*)d_in[0];
    const int*   labels  = (const int*)d_in[1];
    const float* centers = (const float*)d_in[2];
    float* out      = (float*)d_out;
    float* partials = (float*)d_ws;          // 256 floats of scratch

    const int B = in_sizes[1];               // 8192

    center_loss_partial_kernel<<<BLOCKS, THREADS, 0, stream>>>(
        x, labels, centers, partials);
    center_loss_reduce_kernel<<<1, 64, 0, stream>>>(
        partials, out, 1.0f / (float)B);
}